// Round 12
// baseline (417.543 us; speedup 1.0000x reference)
//
#include <hip/hip_runtime.h>
#include <hip/hip_fp16.h>

#define NN   100000
#define NE   1600000
#define NBUCK 391                 // ceil(NN/256) buckets of 256 nodes
#define NW1   512                 // pass-1 workgroups
#define CH1   (NE / NW1)          // 3125 edges per wg
#define GN    (NBUCK * NW1)       // 200192 scan entries
#define SC    512
#define SNB   (GN / SC)           // 391 scan blocks
#define BNB   512                 // bnstats blocks
constexpr float EPSV = 1e-5f;

typedef _Float16 f16x8 __attribute__((ext_vector_type(8)));
typedef float    f32x4 __attribute__((ext_vector_type(4)));

// ---------------- graph prep: 2-level bucket CSR build ----------------

__global__ __launch_bounds__(256) void p1hist_kernel(const int* __restrict__ dst,
                                                     int* __restrict__ G) {
    __shared__ int h[NBUCK];
    int t = threadIdx.x, wg = blockIdx.x;
    for (int i = t; i < NBUCK; i += 256) h[i] = 0;
    __syncthreads();
    int base = wg * CH1;
    for (int e = base + t; e < base + CH1; e += 256)
        atomicAdd(&h[dst[e] >> 8], 1);
    __syncthreads();
    for (int i = t; i < NBUCK; i += 256) G[i * NW1 + wg] = h[i];
}

__global__ __launch_bounds__(256) void gscan1_kernel(const int* __restrict__ G,
                                                     int* __restrict__ bsum) {
    __shared__ int red[256];
    int t = threadIdx.x;
    int base = blockIdx.x * SC + t * 2;
    red[t] = G[base] + G[base + 1];
    __syncthreads();
    #pragma unroll
    for (int off = 128; off > 0; off >>= 1) {
        if (t < off) red[t] += red[t + off];
        __syncthreads();
    }
    if (t == 0) bsum[blockIdx.x] = red[0];
}

__global__ __launch_bounds__(512) void gscan2_kernel(const int* __restrict__ bsum,
                                                     int* __restrict__ boff) {
    __shared__ int s[512];
    int t = threadIdx.x;
    int v = (t < SNB) ? bsum[t] : 0;
    s[t] = v;
    __syncthreads();
    #pragma unroll
    for (int off = 1; off < 512; off <<= 1) {
        int u = (t >= off) ? s[t - off] : 0;
        __syncthreads();
        s[t] += u;
        __syncthreads();
    }
    if (t < SNB) boff[t] = s[t] - v;   // exclusive
}

__global__ __launch_bounds__(256) void gscan3_kernel(int* __restrict__ G,
                                                     const int* __restrict__ boff) {
    __shared__ int s[256];
    int t = threadIdx.x;
    int base = blockIdx.x * SC + t * 2;
    int c0 = G[base], c1 = G[base + 1];
    int pair = c0 + c1;
    s[t] = pair;
    __syncthreads();
    #pragma unroll
    for (int off = 1; off < 256; off <<= 1) {
        int u = (t >= off) ? s[t - off] : 0;
        __syncthreads();
        s[t] += u;
        __syncthreads();
    }
    int excl = boff[blockIdx.x] + s[t] - pair;
    G[base]     = excl;
    G[base + 1] = excl + c0;
}

__global__ __launch_bounds__(256) void p1fill_kernel(const int* __restrict__ src,
                                                     const int* __restrict__ dst,
                                                     const int* __restrict__ G,
                                                     int* __restrict__ ebuf) {
    __shared__ int cur[NBUCK];
    int t = threadIdx.x, wg = blockIdx.x;
    for (int i = t; i < NBUCK; i += 256) cur[i] = G[i * NW1 + wg];
    __syncthreads();
    int base = wg * CH1;
    for (int e = base + t; e < base + CH1; e += 256) {
        int d = dst[e];
        int pos = atomicAdd(&cur[d >> 8], 1);
        ebuf[pos] = src[e] | ((d & 255) << 17);
    }
}

__global__ __launch_bounds__(256) void p2build_kernel(const int* __restrict__ ebuf,
                                                      const int* __restrict__ G,
                                                      int* __restrict__ rowptr,
                                                      int* __restrict__ srcsorted,
                                                      float* __restrict__ dinv) {
    __shared__ int cnt[256];
    __shared__ int s[256];
    __shared__ int cur[256];
    int t = threadIdx.x, b = blockIdx.x;
    int base = G[b * NW1];
    int endp = (b == NBUCK - 1) ? NE : G[(b + 1) * NW1];
    cnt[t] = 0;
    __syncthreads();
    for (int e = base + t; e < endp; e += 256)
        atomicAdd(&cnt[ebuf[e] >> 17], 1);
    __syncthreads();
    int c = cnt[t];
    s[t] = c;
    __syncthreads();
    #pragma unroll
    for (int off = 1; off < 256; off <<= 1) {
        int u = (t >= off) ? s[t - off] : 0;
        __syncthreads();
        s[t] += u;
        __syncthreads();
    }
    int excl = s[t] - c;
    int node = b * 256 + t;
    if (node < NN) {
        rowptr[node] = base + excl;
        dinv[node]   = rsqrtf((float)c + 1.0f);
    }
    cur[t] = base + excl;
    __syncthreads();
    for (int e = base + t; e < endp; e += 256) {
        int p = ebuf[e];
        int pos = atomicAdd(&cur[p >> 17], 1);
        srcsorted[pos] = p & 0x1FFFF;
    }
    if (b == NBUCK - 1 && t == 0) rowptr[NN] = NE;
}

// ---------------- weight prep: W[k][n] fp32 -> Wt[n][k] fp16 ----------------

__global__ void wprep_kernel(const float* __restrict__ W1, const float* __restrict__ W2,
                             __half* __restrict__ Wt) {
    int b = blockIdx.x;
    int layer = b >> 7, n = b & 127, k = threadIdx.x;
    const float* W = layer ? W2 : W1;
    Wt[layer * 16384 + n * 128 + k] = __float2half_rn(W[k * 128 + n]);
}

// ---------------- batchnorm stats: atomic-free 2-stage reduction ----------------

__global__ __launch_bounds__(256) void bnstats_kernel(const __half* __restrict__ X,
                                                      float* __restrict__ partial) {
    __shared__ float red[4][256];
    int t = threadIdx.x;
    int f2 = t & 63, rg = t >> 6;
    const __half2* base = (const __half2*)X + f2;
    float s0 = 0.f, s1 = 0.f, q0 = 0.f, q1 = 0.f;
    for (int r = blockIdx.x * 4 + rg; r < NN; r += BNB * 4) {
        float2 v = __half22float2(base[(size_t)r * 64]);
        s0 += v.x; s1 += v.y; q0 += v.x * v.x; q1 += v.y * v.y;
    }
    red[rg][f2 * 4 + 0] = s0;
    red[rg][f2 * 4 + 1] = s1;
    red[rg][f2 * 4 + 2] = q0;
    red[rg][f2 * 4 + 3] = q1;
    __syncthreads();
    int kind = t >> 7, f = t & 127;
    int slot = (f >> 1) * 4 + (f & 1) + kind * 2;
    float v = red[0][slot] + red[1][slot] + red[2][slot] + red[3][slot];
    partial[blockIdx.x * 256 + kind * 128 + f] = v;
}

__global__ __launch_bounds__(256) void bnfinal_kernel(const float* __restrict__ partial,
                                                      const float* __restrict__ g,
                                                      const float* __restrict__ be,
                                                      float* __restrict__ sc) {
    __shared__ float red[256];
    int t = threadIdx.x;
    float v = 0.f;
    #pragma unroll 8
    for (int sl = 0; sl < BNB; ++sl) v += partial[sl * 256 + t];
    red[t] = v;
    __syncthreads();
    if (t < 128) {
        float s = red[t], q = red[128 + t];
        float mu  = s * (1.0f / NN);
        float var = q * (1.0f / NN) - mu * mu;
        float rstd = rsqrtf(var + EPSV);
        float scale = g[t] * rstd;
        sc[t]       = scale;
        sc[128 + t] = be[t] - mu * scale;
    }
}

// ---------------- MFMA fp16 GEMM: 64 nodes x 128 feats, K=128 ----------------

__device__ __forceinline__ int swzb(int row, int colByte) {
    return row * 256 + (colByte ^ ((row & 7) << 4));
}

template<bool BN, typename TIN>
__global__ __launch_bounds__(256) void gemm128m_kernel(const TIN* __restrict__ X,
        const __half* __restrict__ Wt, const float* __restrict__ sc,
        const float* __restrict__ dinv, __half* __restrict__ Y) {
    __shared__ __align__(16) char Xs[64 * 256];
    __shared__ __align__(16) char Wts[128 * 256];
    __shared__ float dvs[64];
    int tid = threadIdx.x;
    int node0 = blockIdx.x * 64;

    {   // stage Wt (pre-transposed fp16)
        int n = tid >> 1, c0 = (tid & 1) * 64;
        const _Float16* g = (const _Float16*)Wt + n * 128 + c0;
        #pragma unroll
        for (int j = 0; j < 8; ++j) {
            f16x8 v = *(const f16x8*)(g + j * 8);
            *(f16x8*)(Wts + swzb(n, (c0 + j * 8) * 2)) = v;
        }
    }
    {   // stage X (+BN+ReLU), cvt fp16
        int r = tid >> 2, c0 = (tid & 3) * 32;
        int grow = node0 + r;
        #pragma unroll
        for (int j = 0; j < 4; ++j) {
            int c = c0 + j * 8;
            f16x8 o;
            if (grow < NN) {
                float f[8];
                if constexpr (sizeof(TIN) == 4) {
                    float4 u0 = *(const float4*)((const float*)X + (size_t)grow * 128 + c);
                    float4 u1 = *(const float4*)((const float*)X + (size_t)grow * 128 + c + 4);
                    f[0] = u0.x; f[1] = u0.y; f[2] = u0.z; f[3] = u0.w;
                    f[4] = u1.x; f[5] = u1.y; f[6] = u1.z; f[7] = u1.w;
                } else {
                    f16x8 h = *(const f16x8*)((const _Float16*)X + (size_t)grow * 128 + c);
                    #pragma unroll
                    for (int i = 0; i < 8; ++i) f[i] = (float)h[i];
                }
                #pragma unroll
                for (int i = 0; i < 8; ++i) {
                    if constexpr (BN) f[i] = fmaxf(fmaf(f[i], sc[c + i], sc[128 + c + i]), 0.f);
                    o[i] = (_Float16)f[i];
                }
            } else {
                #pragma unroll
                for (int i = 0; i < 8; ++i) o[i] = (_Float16)0.f;
            }
            *(f16x8*)(Xs + swzb(r, c * 2)) = o;
        }
    }
    if (tid < 64) dvs[tid] = (node0 + tid < NN) ? dinv[node0 + tid] : 0.f;
    __syncthreads();

    int lane = tid & 63;
    int wv   = tid >> 6;
    int n0w  = wv * 32;
    int lm   = lane & 15;
    int lg   = lane >> 4;

    f32x4 acc[4][2] = {};
    #pragma unroll
    for (int s = 0; s < 4; ++s) {
        int kb = (s * 32 + lg * 8) * 2;
        f16x8 a[4], b[2];
        #pragma unroll
        for (int i = 0; i < 4; ++i)
            a[i] = *(const f16x8*)(Xs + swzb(i * 16 + lm, kb));
        #pragma unroll
        for (int r = 0; r < 2; ++r)
            b[r] = *(const f16x8*)(Wts + swzb(n0w + r * 16 + lm, kb));
        #pragma unroll
        for (int i = 0; i < 4; ++i)
            #pragma unroll
            for (int r = 0; r < 2; ++r)
                acc[i][r] = __builtin_amdgcn_mfma_f32_16x16x32_f16(a[i], b[r], acc[i][r], 0, 0, 0);
    }

    _Float16* Yh = (_Float16*)Y;
    #pragma unroll
    for (int i = 0; i < 4; ++i) {
        #pragma unroll
        for (int q = 0; q < 4; ++q) {
            int row = i * 16 + lg * 4 + q;
            int grow = node0 + row;
            if (grow < NN) {
                float di = dvs[row];
                Yh[(size_t)grow * 128 + n0w + lm]      = (_Float16)(acc[i][0][q] * di);
                Yh[(size_t)grow * 128 + n0w + 16 + lm] = (_Float16)(acc[i][1][q] * di);
            }
        }
    }
}

// ---------------- final dense GEMM 128->40 (fp32 VALU, fp16 in, pad out 64) ------

__global__ __launch_bounds__(256) void gemm40_kernel(const __half* __restrict__ X,
        const float* __restrict__ W, const float* __restrict__ sc,
        const float* __restrict__ dinv, __half* __restrict__ Y) {
    __shared__ float Ws[128][40];
    __shared__ float Xs[32][132];
    int tx = threadIdx.x, ty = threadIdx.y;
    int tid = ty * 8 + tx;
    int node0 = blockIdx.x * 32;

    float* wf = &Ws[0][0];
    for (int idx = tid; idx < 128 * 40; idx += 256) wf[idx] = W[idx];
    for (int idx = tid * 8; idx < 32 * 128; idx += 256 * 8) {
        int n = idx >> 7, f = idx & 127;
        f16x8 h = *(const f16x8*)((const _Float16*)X + (size_t)(node0 + n) * 128 + f);
        float v[8];
        #pragma unroll
        for (int i = 0; i < 8; ++i)
            v[i] = fmaxf(fmaf((float)h[i], sc[f + i], sc[128 + f + i]), 0.f);
        *(float4*)&Xs[n][f]     = make_float4(v[0], v[1], v[2], v[3]);
        *(float4*)&Xs[n][f + 4] = make_float4(v[4], v[5], v[6], v[7]);
    }
    __syncthreads();

    float acc[5] = {0, 0, 0, 0, 0};
    int f0 = tx * 5;
    #pragma unroll 4
    for (int k = 0; k < 128; ++k) {
        float xv = Xs[ty][k];
        #pragma unroll
        for (int j = 0; j < 5; ++j) acc[j] = fmaf(xv, Ws[k][f0 + j], acc[j]);
    }
    float di = dinv[node0 + ty];
    __half* yp = Y + (size_t)(node0 + ty) * 64;   // padded stride 64
    #pragma unroll
    for (int j = 0; j < 5; ++j) yp[f0 + j] = __float2half_rn(acc[j] * di);
    // zero-fill pad feats 40..63 (3 per tx)
    #pragma unroll
    for (int j = 0; j < 3; ++j) yp[40 + tx * 3 + j] = __float2half_rn(0.f);
}

// ---------------- aggregation: 16B/lane gather, 4 edges per wave-issue ----------
// lane = 16*g + c : g = edge slot (0..3), c = 16-byte chunk (feats c*8..c*8+7)

__global__ __launch_bounds__(256) void agg128_kernel(const __half* __restrict__ H,
        const int* __restrict__ rowptr, const int* __restrict__ srcs,
        const float* __restrict__ dinv, const float* __restrict__ bias,
        __half* __restrict__ Bout) {
    int wave = threadIdx.x >> 6;
    int lane = threadIdx.x & 63;
    int node = blockIdx.x * 4 + wave;
    int beg = rowptr[node], end = rowptr[node + 1];
    int g = lane >> 4;          // edge slot
    int c = lane & 15;          // f16x8 chunk
    const f16x8* Hc = (const f16x8*)H + c;   // row r at Hc[r*16]
    float acc[8] = {};
    int e = beg;
    for (; e + 7 < end; e += 8) {            // 8 rows in flight (4 slots x 2)
        int s0 = srcs[e + g];
        int s1 = srcs[e + 4 + g];
        f16x8 h0 = Hc[(size_t)s0 * 16];
        f16x8 h1 = Hc[(size_t)s1 * 16];
        #pragma unroll
        for (int j = 0; j < 8; ++j) acc[j] += (float)h0[j] + (float)h1[j];
    }
    for (; e + 3 < end; e += 4) {
        int s0 = srcs[e + g];
        f16x8 h0 = Hc[(size_t)s0 * 16];
        #pragma unroll
        for (int j = 0; j < 8; ++j) acc[j] += (float)h0[j];
    }
    if (e + g < end) {
        int s = srcs[e + g];
        f16x8 h = Hc[(size_t)s * 16];
        #pragma unroll
        for (int j = 0; j < 8; ++j) acc[j] += (float)h[j];
    }
    // merge edge slots: xor 16, 32
    #pragma unroll
    for (int j = 0; j < 8; ++j) {
        acc[j] += __shfl_xor(acc[j], 16);
        acc[j] += __shfl_xor(acc[j], 32);
    }
    float di = dinv[node];
    f16x8 hs = Hc[(size_t)node * 16];        // self row (pre-scaled by dinv[node])
    _Float16 o[8];
    #pragma unroll
    for (int j = 0; j < 8; ++j) {
        float v = di * (acc[j] + (float)hs[j]) + bias[c * 8 + j];
        o[j] = (_Float16)v;
    }
    if (g == 0)
        *((f16x8*)Bout + (size_t)node * 16 + c) = *(f16x8*)o;
}

// final: padded-64 rows; lane = 8*g + c, c<5 are real chunks (feats c*8..+8)
__global__ __launch_bounds__(256) void agg40_softmax_kernel(const __half* __restrict__ H,
        const int* __restrict__ rowptr, const int* __restrict__ srcs,
        const float* __restrict__ dinv, const float* __restrict__ bias,
        float* __restrict__ out) {
    int wave = threadIdx.x >> 6;
    int lane = threadIdx.x & 63;
    int node = blockIdx.x * 4 + wave;
    int beg = rowptr[node], end = rowptr[node + 1];
    int g = lane >> 3;          // edge slot 0..7
    int c = lane & 7;           // chunk; real if c<5
    const f16x8* Hc = (const f16x8*)H + c;   // row r at Hc[r*8]
    float acc[8] = {};
    int e = beg;
    for (; e + 15 < end; e += 16) {          // 16 rows in flight (8 slots x 2)
        int s0 = srcs[e + g];
        int s1 = srcs[e + 8 + g];
        f16x8 h0 = Hc[(size_t)s0 * 8];
        f16x8 h1 = Hc[(size_t)s1 * 8];
        #pragma unroll
        for (int j = 0; j < 8; ++j) acc[j] += (float)h0[j] + (float)h1[j];
    }
    for (; e + 7 < end; e += 8) {
        int s0 = srcs[e + g];
        f16x8 h0 = Hc[(size_t)s0 * 8];
        #pragma unroll
        for (int j = 0; j < 8; ++j) acc[j] += (float)h0[j];
    }
    if (e + g < end) {
        int s = srcs[e + g];
        f16x8 h = Hc[(size_t)s * 8];
        #pragma unroll
        for (int j = 0; j < 8; ++j) acc[j] += (float)h[j];
    }
    // merge edge slots: xor 8, 16, 32
    #pragma unroll
    for (int j = 0; j < 8; ++j) {
        acc[j] += __shfl_xor(acc[j], 8);
        acc[j] += __shfl_xor(acc[j], 16);
        acc[j] += __shfl_xor(acc[j], 32);
    }
    float di = dinv[node];
    f16x8 hs = Hc[(size_t)node * 8];
    bool real = c < 5;
    float v[8];
    float mloc = -3.0e38f;
    #pragma unroll
    for (int j = 0; j < 8; ++j) {
        float b = real ? bias[c * 8 + j] : 0.f;   // c<5 => c*8+j <= 39
        v[j] = di * (acc[j] + (float)hs[j]) + b;
        if (real) mloc = fmaxf(mloc, v[j]);
    }
    // cross-chunk reduce over c (bits 0..2)
    mloc = fmaxf(mloc, __shfl_xor(mloc, 1));
    mloc = fmaxf(mloc, __shfl_xor(mloc, 2));
    mloc = fmaxf(mloc, __shfl_xor(mloc, 4));
    float ev[8];
    float sloc = 0.f;
    #pragma unroll
    for (int j = 0; j < 8; ++j) {
        ev[j] = real ? expf(v[j] - mloc) : 0.f;
        sloc += ev[j];
    }
    sloc += __shfl_xor(sloc, 1);
    sloc += __shfl_xor(sloc, 2);
    sloc += __shfl_xor(sloc, 4);
    float inv = 1.0f / sloc;
    if (g == 0 && real) {
        float* op = out + (size_t)node * 40 + c * 8;
        *(float4*)op       = make_float4(ev[0] * inv, ev[1] * inv, ev[2] * inv, ev[3] * inv);
        *(float4*)(op + 4) = make_float4(ev[4] * inv, ev[5] * inv, ev[6] * inv, ev[7] * inv);
    }
}

// ---------------- launch ----------------

extern "C" void kernel_launch(void* const* d_in, const int* in_sizes, int n_in,
                              void* d_out, int out_size, void* d_ws, size_t ws_size,
                              hipStream_t stream) {
    const float* x   = (const float*)d_in[0];
    const int*   ei  = (const int*)d_in[1];
    const float* W1  = (const float*)d_in[2];
    const float* b1  = (const float*)d_in[3];
    const float* g1  = (const float*)d_in[4];
    const float* be1 = (const float*)d_in[5];
    const float* W2  = (const float*)d_in[6];
    const float* b2  = (const float*)d_in[7];
    const float* g2  = (const float*)d_in[8];
    const float* be2 = (const float*)d_in[9];
    const float* W3  = (const float*)d_in[10];
    const float* b3  = (const float*)d_in[11];
    float* out = (float*)d_out;
    const int* src = ei;
    const int* dst = ei + NE;

    char* p = (char*)d_ws;
    auto alloc = [&](size_t bytes) { char* r = p; p += (bytes + 255) & ~255ull; return r; };
    int*    rowptr    = (int*)   alloc((size_t)(NN + 1) * 4);
    int*    srcsorted = (int*)   alloc((size_t)NE * 4);
    float*  dinv      = (float*) alloc((size_t)NN * 4);
    float*  sc        = (float*) alloc(256 * 4);
    int*    G         = (int*)   alloc((size_t)GN * 4);
    int*    bsum      = (int*)   alloc((size_t)SNB * 4);
    int*    boff      = (int*)   alloc((size_t)SNB * 4);
    float*  partial   = (float*) alloc((size_t)BNB * 256 * 4);
    __half* Wth       = (__half*)alloc((size_t)2 * 16384 * 2);
    __half* A         = (__half*)alloc((size_t)NN * 128 * 2);
    __half* Bh        = (__half*)alloc((size_t)NN * 128 * 2);
    int*    ebuf      = (int*)A;   // A unused until layer-1 GEMM

    // prep
    wprep_kernel<<<256, 128, 0, stream>>>(W1, W2, Wth);
    p1hist_kernel<<<NW1, 256, 0, stream>>>(dst, G);
    gscan1_kernel<<<SNB, 256, 0, stream>>>(G, bsum);
    gscan2_kernel<<<1, 512, 0, stream>>>(bsum, boff);
    gscan3_kernel<<<SNB, 256, 0, stream>>>(G, boff);
    p1fill_kernel<<<NW1, 256, 0, stream>>>(src, dst, G, ebuf);
    p2build_kernel<<<NBUCK, 256, 0, stream>>>(ebuf, G, rowptr, srcsorted, dinv);

    const int GB = (NN + 63) / 64;   // 1563
    // layer 1
    gemm128m_kernel<false, float><<<GB, 256, 0, stream>>>(x, Wth, nullptr, dinv, A);
    agg128_kernel<<<NN / 4, 256, 0, stream>>>(A, rowptr, srcsorted, dinv, b1, Bh);
    bnstats_kernel<<<BNB, 256, 0, stream>>>(Bh, partial);
    bnfinal_kernel<<<1, 256, 0, stream>>>(partial, g1, be1, sc);
    // layer 2
    gemm128m_kernel<true, __half><<<GB, 256, 0, stream>>>(Bh, Wth + 16384, sc, dinv, A);
    agg128_kernel<<<NN / 4, 256, 0, stream>>>(A, rowptr, srcsorted, dinv, b2, Bh);
    bnstats_kernel<<<BNB, 256, 0, stream>>>(Bh, partial);
    bnfinal_kernel<<<1, 256, 0, stream>>>(partial, g2, be2, sc);
    // layer 3 (gemm40 writes zero-padded 64-stride rows into A)
    gemm40_kernel<<<NN / 32, dim3(8, 32), 0, stream>>>(Bh, W3, sc, dinv, A);
    agg40_softmax_kernel<<<NN / 4, 256, 0, stream>>>(A, rowptr, srcsorted, dinv, b3, out);
}

// Round 13
// 402.824 us; speedup vs baseline: 1.0365x; 1.0365x over previous
//
#include <hip/hip_runtime.h>
#include <hip/hip_fp16.h>

#define NN   100000
#define NE   1600000
#define NBUCK 391                 // ceil(NN/256) buckets of 256 nodes
#define NW1   512                 // pass-1 workgroups
#define CH1   (NE / NW1)          // 3125 edges per wg
#define GN    (NBUCK * NW1)       // 200192 scan entries
#define SC    512
#define SNB   (GN / SC)           // 391 scan blocks
#define BNB   512                 // bnstats blocks
constexpr float EPSV = 1e-5f;

typedef _Float16 f16x8 __attribute__((ext_vector_type(8)));
typedef float    f32x4 __attribute__((ext_vector_type(4)));

// ---------------- graph prep: 2-level bucket CSR build ----------------

__global__ __launch_bounds__(256) void p1hist_kernel(const int* __restrict__ dst,
                                                     int* __restrict__ G) {
    __shared__ int h[NBUCK];
    int t = threadIdx.x, wg = blockIdx.x;
    for (int i = t; i < NBUCK; i += 256) h[i] = 0;
    __syncthreads();
    int base = wg * CH1;
    for (int e = base + t; e < base + CH1; e += 256)
        atomicAdd(&h[dst[e] >> 8], 1);
    __syncthreads();
    for (int i = t; i < NBUCK; i += 256) G[i * NW1 + wg] = h[i];
}

__global__ __launch_bounds__(256) void gscan1_kernel(const int* __restrict__ G,
                                                     int* __restrict__ bsum) {
    __shared__ int red[256];
    int t = threadIdx.x;
    int base = blockIdx.x * SC + t * 2;
    red[t] = G[base] + G[base + 1];
    __syncthreads();
    #pragma unroll
    for (int off = 128; off > 0; off >>= 1) {
        if (t < off) red[t] += red[t + off];
        __syncthreads();
    }
    if (t == 0) bsum[blockIdx.x] = red[0];
}

__global__ __launch_bounds__(512) void gscan2_kernel(const int* __restrict__ bsum,
                                                     int* __restrict__ boff) {
    __shared__ int s[512];
    int t = threadIdx.x;
    int v = (t < SNB) ? bsum[t] : 0;
    s[t] = v;
    __syncthreads();
    #pragma unroll
    for (int off = 1; off < 512; off <<= 1) {
        int u = (t >= off) ? s[t - off] : 0;
        __syncthreads();
        s[t] += u;
        __syncthreads();
    }
    if (t < SNB) boff[t] = s[t] - v;   // exclusive
}

__global__ __launch_bounds__(256) void gscan3_kernel(int* __restrict__ G,
                                                     const int* __restrict__ boff) {
    __shared__ int s[256];
    int t = threadIdx.x;
    int base = blockIdx.x * SC + t * 2;
    int c0 = G[base], c1 = G[base + 1];
    int pair = c0 + c1;
    s[t] = pair;
    __syncthreads();
    #pragma unroll
    for (int off = 1; off < 256; off <<= 1) {
        int u = (t >= off) ? s[t - off] : 0;
        __syncthreads();
        s[t] += u;
        __syncthreads();
    }
    int excl = boff[blockIdx.x] + s[t] - pair;
    G[base]     = excl;
    G[base + 1] = excl + c0;
}

__global__ __launch_bounds__(256) void p1fill_kernel(const int* __restrict__ src,
                                                     const int* __restrict__ dst,
                                                     const int* __restrict__ G,
                                                     int* __restrict__ ebuf) {
    __shared__ int cur[NBUCK];
    int t = threadIdx.x, wg = blockIdx.x;
    for (int i = t; i < NBUCK; i += 256) cur[i] = G[i * NW1 + wg];
    __syncthreads();
    int base = wg * CH1;
    for (int e = base + t; e < base + CH1; e += 256) {
        int d = dst[e];
        int pos = atomicAdd(&cur[d >> 8], 1);
        ebuf[pos] = src[e] | ((d & 255) << 17);
    }
}

__global__ __launch_bounds__(256) void p2build_kernel(const int* __restrict__ ebuf,
                                                      const int* __restrict__ G,
                                                      int* __restrict__ rowptr,
                                                      int* __restrict__ srcsorted,
                                                      float* __restrict__ dinv) {
    __shared__ int cnt[256];
    __shared__ int s[256];
    __shared__ int cur[256];
    int t = threadIdx.x, b = blockIdx.x;
    int base = G[b * NW1];
    int endp = (b == NBUCK - 1) ? NE : G[(b + 1) * NW1];
    cnt[t] = 0;
    __syncthreads();
    for (int e = base + t; e < endp; e += 256)
        atomicAdd(&cnt[ebuf[e] >> 17], 1);
    __syncthreads();
    int c = cnt[t];
    s[t] = c;
    __syncthreads();
    #pragma unroll
    for (int off = 1; off < 256; off <<= 1) {
        int u = (t >= off) ? s[t - off] : 0;
        __syncthreads();
        s[t] += u;
        __syncthreads();
    }
    int excl = s[t] - c;
    int node = b * 256 + t;
    if (node < NN) {
        rowptr[node] = base + excl;
        dinv[node]   = rsqrtf((float)c + 1.0f);
    }
    cur[t] = base + excl;
    __syncthreads();
    for (int e = base + t; e < endp; e += 256) {
        int p = ebuf[e];
        int pos = atomicAdd(&cur[p >> 17], 1);
        srcsorted[pos] = p & 0x1FFFF;
    }
    if (b == NBUCK - 1 && t == 0) rowptr[NN] = NE;
}

// ---------------- weight prep: W[k][n] fp32 -> Wt[n][k] fp16 ----------------

__global__ void wprep_kernel(const float* __restrict__ W1, const float* __restrict__ W2,
                             __half* __restrict__ Wt) {
    int b = blockIdx.x;
    int layer = b >> 7, n = b & 127, k = threadIdx.x;
    const float* W = layer ? W2 : W1;
    Wt[layer * 16384 + n * 128 + k] = __float2half_rn(W[k * 128 + n]);
}

// ---------------- batchnorm stats: atomic-free 2-stage reduction ----------------

__global__ __launch_bounds__(256) void bnstats_kernel(const __half* __restrict__ X,
                                                      float* __restrict__ partial) {
    __shared__ float red[4][256];
    int t = threadIdx.x;
    int f2 = t & 63, rg = t >> 6;
    const __half2* base = (const __half2*)X + f2;
    float s0 = 0.f, s1 = 0.f, q0 = 0.f, q1 = 0.f;
    for (int r = blockIdx.x * 4 + rg; r < NN; r += BNB * 4) {
        float2 v = __half22float2(base[(size_t)r * 64]);
        s0 += v.x; s1 += v.y; q0 += v.x * v.x; q1 += v.y * v.y;
    }
    red[rg][f2 * 4 + 0] = s0;
    red[rg][f2 * 4 + 1] = s1;
    red[rg][f2 * 4 + 2] = q0;
    red[rg][f2 * 4 + 3] = q1;
    __syncthreads();
    int kind = t >> 7, f = t & 127;
    int slot = (f >> 1) * 4 + (f & 1) + kind * 2;
    float v = red[0][slot] + red[1][slot] + red[2][slot] + red[3][slot];
    partial[blockIdx.x * 256 + kind * 128 + f] = v;
}

__global__ __launch_bounds__(256) void bnfinal_kernel(const float* __restrict__ partial,
                                                      const float* __restrict__ g,
                                                      const float* __restrict__ be,
                                                      float* __restrict__ sc) {
    __shared__ float red[256];
    int t = threadIdx.x;
    float v = 0.f;
    #pragma unroll 8
    for (int sl = 0; sl < BNB; ++sl) v += partial[sl * 256 + t];
    red[t] = v;
    __syncthreads();
    if (t < 128) {
        float s = red[t], q = red[128 + t];
        float mu  = s * (1.0f / NN);
        float var = q * (1.0f / NN) - mu * mu;
        float rstd = rsqrtf(var + EPSV);
        float scale = g[t] * rstd;
        sc[t]       = scale;
        sc[128 + t] = be[t] - mu * scale;
    }
}

// ---------------- MFMA fp16 GEMM: 64 nodes x 128 feats, K=128 ----------------

__device__ __forceinline__ int swzb(int row, int colByte) {
    return row * 256 + (colByte ^ ((row & 7) << 4));
}

template<bool BN, typename TIN>
__global__ __launch_bounds__(256) void gemm128m_kernel(const TIN* __restrict__ X,
        const __half* __restrict__ Wt, const float* __restrict__ sc,
        const float* __restrict__ dinv, __half* __restrict__ Y) {
    __shared__ __align__(16) char Xs[64 * 256];
    __shared__ __align__(16) char Wts[128 * 256];
    __shared__ float dvs[64];
    int tid = threadIdx.x;
    int node0 = blockIdx.x * 64;

    {   // stage Wt (pre-transposed fp16)
        int n = tid >> 1, c0 = (tid & 1) * 64;
        const _Float16* g = (const _Float16*)Wt + n * 128 + c0;
        #pragma unroll
        for (int j = 0; j < 8; ++j) {
            f16x8 v = *(const f16x8*)(g + j * 8);
            *(f16x8*)(Wts + swzb(n, (c0 + j * 8) * 2)) = v;
        }
    }
    {   // stage X (+BN+ReLU), cvt fp16
        int r = tid >> 2, c0 = (tid & 3) * 32;
        int grow = node0 + r;
        #pragma unroll
        for (int j = 0; j < 4; ++j) {
            int c = c0 + j * 8;
            f16x8 o;
            if (grow < NN) {
                float f[8];
                if constexpr (sizeof(TIN) == 4) {
                    float4 u0 = *(const float4*)((const float*)X + (size_t)grow * 128 + c);
                    float4 u1 = *(const float4*)((const float*)X + (size_t)grow * 128 + c + 4);
                    f[0] = u0.x; f[1] = u0.y; f[2] = u0.z; f[3] = u0.w;
                    f[4] = u1.x; f[5] = u1.y; f[6] = u1.z; f[7] = u1.w;
                } else {
                    f16x8 h = *(const f16x8*)((const _Float16*)X + (size_t)grow * 128 + c);
                    #pragma unroll
                    for (int i = 0; i < 8; ++i) f[i] = (float)h[i];
                }
                #pragma unroll
                for (int i = 0; i < 8; ++i) {
                    if constexpr (BN) f[i] = fmaxf(fmaf(f[i], sc[c + i], sc[128 + c + i]), 0.f);
                    o[i] = (_Float16)f[i];
                }
            } else {
                #pragma unroll
                for (int i = 0; i < 8; ++i) o[i] = (_Float16)0.f;
            }
            *(f16x8*)(Xs + swzb(r, c * 2)) = o;
        }
    }
    if (tid < 64) dvs[tid] = (node0 + tid < NN) ? dinv[node0 + tid] : 0.f;
    __syncthreads();

    int lane = tid & 63;
    int wv   = tid >> 6;
    int n0w  = wv * 32;
    int lm   = lane & 15;
    int lg   = lane >> 4;

    f32x4 acc[4][2] = {};
    #pragma unroll
    for (int s = 0; s < 4; ++s) {
        int kb = (s * 32 + lg * 8) * 2;
        f16x8 a[4], b[2];
        #pragma unroll
        for (int i = 0; i < 4; ++i)
            a[i] = *(const f16x8*)(Xs + swzb(i * 16 + lm, kb));
        #pragma unroll
        for (int r = 0; r < 2; ++r)
            b[r] = *(const f16x8*)(Wts + swzb(n0w + r * 16 + lm, kb));
        #pragma unroll
        for (int i = 0; i < 4; ++i)
            #pragma unroll
            for (int r = 0; r < 2; ++r)
                acc[i][r] = __builtin_amdgcn_mfma_f32_16x16x32_f16(a[i], b[r], acc[i][r], 0, 0, 0);
    }

    _Float16* Yh = (_Float16*)Y;
    #pragma unroll
    for (int i = 0; i < 4; ++i) {
        #pragma unroll
        for (int q = 0; q < 4; ++q) {
            int row = i * 16 + lg * 4 + q;
            int grow = node0 + row;
            if (grow < NN) {
                float di = dvs[row];
                Yh[(size_t)grow * 128 + n0w + lm]      = (_Float16)(acc[i][0][q] * di);
                Yh[(size_t)grow * 128 + n0w + 16 + lm] = (_Float16)(acc[i][1][q] * di);
            }
        }
    }
}

// ---------------- final dense GEMM 128->40 (fp32 VALU, fp16 in, pad out 64) ------

__global__ __launch_bounds__(256) void gemm40_kernel(const __half* __restrict__ X,
        const float* __restrict__ W, const float* __restrict__ sc,
        const float* __restrict__ dinv, __half* __restrict__ Y) {
    __shared__ float Ws[128][40];
    __shared__ float Xs[32][132];
    int tx = threadIdx.x, ty = threadIdx.y;
    int tid = ty * 8 + tx;
    int node0 = blockIdx.x * 32;

    float* wf = &Ws[0][0];
    for (int idx = tid; idx < 128 * 40; idx += 256) wf[idx] = W[idx];
    for (int idx = tid * 8; idx < 32 * 128; idx += 256 * 8) {
        int n = idx >> 7, f = idx & 127;
        f16x8 h = *(const f16x8*)((const _Float16*)X + (size_t)(node0 + n) * 128 + f);
        float v[8];
        #pragma unroll
        for (int i = 0; i < 8; ++i)
            v[i] = fmaxf(fmaf((float)h[i], sc[f + i], sc[128 + f + i]), 0.f);
        *(float4*)&Xs[n][f]     = make_float4(v[0], v[1], v[2], v[3]);
        *(float4*)&Xs[n][f + 4] = make_float4(v[4], v[5], v[6], v[7]);
    }
    __syncthreads();

    float acc[5] = {0, 0, 0, 0, 0};
    int f0 = tx * 5;
    #pragma unroll 4
    for (int k = 0; k < 128; ++k) {
        float xv = Xs[ty][k];
        #pragma unroll
        for (int j = 0; j < 5; ++j) acc[j] = fmaf(xv, Ws[k][f0 + j], acc[j]);
    }
    float di = dinv[node0 + ty];
    __half* yp = Y + (size_t)(node0 + ty) * 64;   // padded stride 64
    #pragma unroll
    for (int j = 0; j < 5; ++j) yp[f0 + j] = __float2half_rn(acc[j] * di);
    // zero-fill pad feats 40..63 (3 per tx)
    #pragma unroll
    for (int j = 0; j < 3; ++j) yp[40 + tx * 3 + j] = __float2half_rn(0.f);
}

// ---------------- agg128: 16B/lane gather, 4 edges per wave-issue ----------
// lane = 16*g + c : g = edge slot (0..3), c = 16-byte chunk (feats c*8..c*8+7)

__global__ __launch_bounds__(256) void agg128_kernel(const __half* __restrict__ H,
        const int* __restrict__ rowptr, const int* __restrict__ srcs,
        const float* __restrict__ dinv, const float* __restrict__ bias,
        __half* __restrict__ Bout) {
    int wave = threadIdx.x >> 6;
    int lane = threadIdx.x & 63;
    int node = blockIdx.x * 4 + wave;
    int beg = rowptr[node], end = rowptr[node + 1];
    int g = lane >> 4;          // edge slot
    int c = lane & 15;          // f16x8 chunk
    const f16x8* Hc = (const f16x8*)H + c;   // row r at Hc[r*16]
    float acc[8] = {};
    int e = beg;
    for (; e + 7 < end; e += 8) {            // 8 rows in flight (4 slots x 2)
        int s0 = srcs[e + g];
        int s1 = srcs[e + 4 + g];
        f16x8 h0 = Hc[(size_t)s0 * 16];
        f16x8 h1 = Hc[(size_t)s1 * 16];
        #pragma unroll
        for (int j = 0; j < 8; ++j) acc[j] += (float)h0[j] + (float)h1[j];
    }
    for (; e + 3 < end; e += 4) {
        int s0 = srcs[e + g];
        f16x8 h0 = Hc[(size_t)s0 * 16];
        #pragma unroll
        for (int j = 0; j < 8; ++j) acc[j] += (float)h0[j];
    }
    if (e + g < end) {
        int s = srcs[e + g];
        f16x8 h = Hc[(size_t)s * 16];
        #pragma unroll
        for (int j = 0; j < 8; ++j) acc[j] += (float)h[j];
    }
    // merge edge slots: xor 16, 32
    #pragma unroll
    for (int j = 0; j < 8; ++j) {
        acc[j] += __shfl_xor(acc[j], 16);
        acc[j] += __shfl_xor(acc[j], 32);
    }
    float di = dinv[node];
    f16x8 hs = Hc[(size_t)node * 16];        // self row (pre-scaled by dinv[node])
    _Float16 o[8];
    #pragma unroll
    for (int j = 0; j < 8; ++j) {
        float v = di * (acc[j] + (float)hs[j]) + bias[c * 8 + j];
        o[j] = (_Float16)v;
    }
    if (g == 0)
        *((f16x8*)Bout + (size_t)node * 16 + c) = *(f16x8*)o;
}

// ---------------- agg40: lane-per-feature scalar gather (R11 structure) ---------
// padded 64-stride rows, 8-deep ILP, cheap wave softmax

__global__ __launch_bounds__(256) void agg40_softmax_kernel(const __half* __restrict__ H,
        const int* __restrict__ rowptr, const int* __restrict__ srcs,
        const float* __restrict__ dinv, const float* __restrict__ bias,
        float* __restrict__ out) {
    int wave = threadIdx.x >> 6;
    int lane = threadIdx.x & 63;
    int node = blockIdx.x * 4 + wave;
    int beg = rowptr[node], end = rowptr[node + 1];
    bool act = lane < 40;
    const _Float16* Hc = (const _Float16*)H + lane;   // padded stride 64
    float a0 = 0.f, a1 = 0.f, a2 = 0.f, a3 = 0.f;
    float a4 = 0.f, a5 = 0.f, a6 = 0.f, a7 = 0.f;
    int e = beg;
    for (; e + 7 < end; e += 8) {
        a0 += (float)Hc[(size_t)srcs[e]     * 64];
        a1 += (float)Hc[(size_t)srcs[e + 1] * 64];
        a2 += (float)Hc[(size_t)srcs[e + 2] * 64];
        a3 += (float)Hc[(size_t)srcs[e + 3] * 64];
        a4 += (float)Hc[(size_t)srcs[e + 4] * 64];
        a5 += (float)Hc[(size_t)srcs[e + 5] * 64];
        a6 += (float)Hc[(size_t)srcs[e + 6] * 64];
        a7 += (float)Hc[(size_t)srcs[e + 7] * 64];
    }
    if (e + 3 < end) {
        a0 += (float)Hc[(size_t)srcs[e]     * 64];
        a1 += (float)Hc[(size_t)srcs[e + 1] * 64];
        a2 += (float)Hc[(size_t)srcs[e + 2] * 64];
        a3 += (float)Hc[(size_t)srcs[e + 3] * 64];
        e += 4;
    }
    for (; e < end; ++e) a0 += (float)Hc[(size_t)srcs[e] * 64];
    float di = dinv[node];
    float hs = (float)Hc[(size_t)node * 64];
    float v = act ? (di * (a0 + a1 + a2 + a3 + a4 + a5 + a6 + a7 + hs) + bias[lane]) : -3.0e38f;
    float m = v;
    #pragma unroll
    for (int off = 32; off > 0; off >>= 1) m = fmaxf(m, __shfl_xor(m, off));
    float ev = act ? expf(v - m) : 0.f;
    float ssum = ev;
    #pragma unroll
    for (int off = 32; off > 0; off >>= 1) ssum += __shfl_xor(ssum, off);
    if (act) out[(size_t)node * 40 + lane] = ev / ssum;
}

// ---------------- launch ----------------

extern "C" void kernel_launch(void* const* d_in, const int* in_sizes, int n_in,
                              void* d_out, int out_size, void* d_ws, size_t ws_size,
                              hipStream_t stream) {
    const float* x   = (const float*)d_in[0];
    const int*   ei  = (const int*)d_in[1];
    const float* W1  = (const float*)d_in[2];
    const float* b1  = (const float*)d_in[3];
    const float* g1  = (const float*)d_in[4];
    const float* be1 = (const float*)d_in[5];
    const float* W2  = (const float*)d_in[6];
    const float* b2  = (const float*)d_in[7];
    const float* g2  = (const float*)d_in[8];
    const float* be2 = (const float*)d_in[9];
    const float* W3  = (const float*)d_in[10];
    const float* b3  = (const float*)d_in[11];
    float* out = (float*)d_out;
    const int* src = ei;
    const int* dst = ei + NE;

    char* p = (char*)d_ws;
    auto alloc = [&](size_t bytes) { char* r = p; p += (bytes + 255) & ~255ull; return r; };
    int*    rowptr    = (int*)   alloc((size_t)(NN + 1) * 4);
    int*    srcsorted = (int*)   alloc((size_t)NE * 4);
    float*  dinv      = (float*) alloc((size_t)NN * 4);
    float*  sc        = (float*) alloc(256 * 4);
    int*    G         = (int*)   alloc((size_t)GN * 4);
    int*    bsum      = (int*)   alloc((size_t)SNB * 4);
    int*    boff      = (int*)   alloc((size_t)SNB * 4);
    float*  partial   = (float*) alloc((size_t)BNB * 256 * 4);
    __half* Wth       = (__half*)alloc((size_t)2 * 16384 * 2);
    __half* A         = (__half*)alloc((size_t)NN * 128 * 2);
    __half* Bh        = (__half*)alloc((size_t)NN * 128 * 2);
    int*    ebuf      = (int*)A;   // A unused until layer-1 GEMM

    // prep
    wprep_kernel<<<256, 128, 0, stream>>>(W1, W2, Wth);
    p1hist_kernel<<<NW1, 256, 0, stream>>>(dst, G);
    gscan1_kernel<<<SNB, 256, 0, stream>>>(G, bsum);
    gscan2_kernel<<<1, 512, 0, stream>>>(bsum, boff);
    gscan3_kernel<<<SNB, 256, 0, stream>>>(G, boff);
    p1fill_kernel<<<NW1, 256, 0, stream>>>(src, dst, G, ebuf);
    p2build_kernel<<<NBUCK, 256, 0, stream>>>(ebuf, G, rowptr, srcsorted, dinv);

    const int GB = (NN + 63) / 64;   // 1563
    // layer 1
    gemm128m_kernel<false, float><<<GB, 256, 0, stream>>>(x, Wth, nullptr, dinv, A);
    agg128_kernel<<<NN / 4, 256, 0, stream>>>(A, rowptr, srcsorted, dinv, b1, Bh);
    bnstats_kernel<<<BNB, 256, 0, stream>>>(Bh, partial);
    bnfinal_kernel<<<1, 256, 0, stream>>>(partial, g1, be1, sc);
    // layer 2
    gemm128m_kernel<true, __half><<<GB, 256, 0, stream>>>(Bh, Wth + 16384, sc, dinv, A);
    agg128_kernel<<<NN / 4, 256, 0, stream>>>(A, rowptr, srcsorted, dinv, b2, Bh);
    bnstats_kernel<<<BNB, 256, 0, stream>>>(Bh, partial);
    bnfinal_kernel<<<1, 256, 0, stream>>>(partial, g2, be2, sc);
    // layer 3 (gemm40 writes zero-padded 64-stride rows into A)
    gemm40_kernel<<<NN / 32, dim3(8, 32), 0, stream>>>(Bh, W3, sc, dinv, A);
    agg40_softmax_kernel<<<NN / 4, 256, 0, stream>>>(A, rowptr, srcsorted, dinv, b3, out);
}

// Round 14
// 401.267 us; speedup vs baseline: 1.0406x; 1.0039x over previous
//
#include <hip/hip_runtime.h>
#include <hip/hip_fp16.h>

#define NN   100000
#define NE   1600000
#define NBUCK 391                 // ceil(NN/256) buckets of 256 nodes
#define NW1   512                 // pass-1 workgroups
#define CH1   (NE / NW1)          // 3125 edges per wg
#define GN    (NBUCK * NW1)       // 200192 scan entries
#define SC    512
#define SNB   (GN / SC)           // 391 scan blocks
#define BNB   512                 // bnstats blocks
constexpr float EPSV = 1e-5f;

typedef _Float16 f16x8 __attribute__((ext_vector_type(8)));
typedef float    f32x4 __attribute__((ext_vector_type(4)));

// ---------------- graph prep: 2-level bucket CSR build ----------------

__global__ __launch_bounds__(256) void p1hist_kernel(const int* __restrict__ dst,
                                                     int* __restrict__ G) {
    __shared__ int h[NBUCK];
    int t = threadIdx.x, wg = blockIdx.x;
    for (int i = t; i < NBUCK; i += 256) h[i] = 0;
    __syncthreads();
    int base = wg * CH1;
    for (int e = base + t; e < base + CH1; e += 256)
        atomicAdd(&h[dst[e] >> 8], 1);
    __syncthreads();
    for (int i = t; i < NBUCK; i += 256) G[i * NW1 + wg] = h[i];
}

__global__ __launch_bounds__(256) void gscan1_kernel(const int* __restrict__ G,
                                                     int* __restrict__ bsum) {
    __shared__ int red[256];
    int t = threadIdx.x;
    int base = blockIdx.x * SC + t * 2;
    red[t] = G[base] + G[base + 1];
    __syncthreads();
    #pragma unroll
    for (int off = 128; off > 0; off >>= 1) {
        if (t < off) red[t] += red[t + off];
        __syncthreads();
    }
    if (t == 0) bsum[blockIdx.x] = red[0];
}

// scan of G in place; each block self-computes its prefix from bsum
__global__ __launch_bounds__(256) void gscan3_kernel(int* __restrict__ G,
                                                     const int* __restrict__ bsum) {
    __shared__ int pre[256];
    __shared__ int s[256];
    int t = threadIdx.x;
    int part = 0;
    for (int j = t; j < (int)blockIdx.x; j += 256) part += bsum[j];
    pre[t] = part;
    __syncthreads();
    #pragma unroll
    for (int off = 128; off > 0; off >>= 1) {
        if (t < off) pre[t] += pre[t + off];
        __syncthreads();
    }
    int boffv = pre[0];
    int base = blockIdx.x * SC + t * 2;
    int c0 = G[base], c1 = G[base + 1];
    int pair = c0 + c1;
    s[t] = pair;
    __syncthreads();
    #pragma unroll
    for (int off = 1; off < 256; off <<= 1) {
        int u = (t >= off) ? s[t - off] : 0;
        __syncthreads();
        s[t] += u;
        __syncthreads();
    }
    int excl = boffv + s[t] - pair;
    G[base]     = excl;
    G[base + 1] = excl + c0;
}

__global__ __launch_bounds__(256) void p1fill_kernel(const int* __restrict__ src,
                                                     const int* __restrict__ dst,
                                                     const int* __restrict__ G,
                                                     int* __restrict__ ebuf) {
    __shared__ int cur[NBUCK];
    int t = threadIdx.x, wg = blockIdx.x;
    for (int i = t; i < NBUCK; i += 256) cur[i] = G[i * NW1 + wg];
    __syncthreads();
    int base = wg * CH1;
    for (int e = base + t; e < base + CH1; e += 256) {
        int d = dst[e];
        int pos = atomicAdd(&cur[d >> 8], 1);
        ebuf[pos] = src[e] | ((d & 255) << 17);
    }
}

__global__ __launch_bounds__(256) void p2build_kernel(const int* __restrict__ ebuf,
                                                      const int* __restrict__ G,
                                                      int* __restrict__ rowptr,
                                                      int* __restrict__ srcsorted,
                                                      float* __restrict__ dinv) {
    __shared__ int cnt[256];
    __shared__ int s[256];
    __shared__ int cur[256];
    int t = threadIdx.x, b = blockIdx.x;
    int base = G[b * NW1];
    int endp = (b == NBUCK - 1) ? NE : G[(b + 1) * NW1];
    cnt[t] = 0;
    __syncthreads();
    for (int e = base + t; e < endp; e += 256)
        atomicAdd(&cnt[ebuf[e] >> 17], 1);
    __syncthreads();
    int c = cnt[t];
    s[t] = c;
    __syncthreads();
    #pragma unroll
    for (int off = 1; off < 256; off <<= 1) {
        int u = (t >= off) ? s[t - off] : 0;
        __syncthreads();
        s[t] += u;
        __syncthreads();
    }
    int excl = s[t] - c;
    int node = b * 256 + t;
    if (node < NN) {
        rowptr[node] = base + excl;
        dinv[node]   = rsqrtf((float)c + 1.0f);
    }
    cur[t] = base + excl;
    __syncthreads();
    for (int e = base + t; e < endp; e += 256) {
        int p = ebuf[e];
        int pos = atomicAdd(&cur[p >> 17], 1);
        srcsorted[pos] = p & 0x1FFFF;
    }
    if (b == NBUCK - 1 && t == 0) rowptr[NN] = NE;
}

// ---------------- weight prep: W[k][n] fp32 -> Wt[n][k] fp16 ----------------

__global__ void wprep_kernel(const float* __restrict__ W1, const float* __restrict__ W2,
                             __half* __restrict__ Wt) {
    int b = blockIdx.x;
    int layer = b >> 7, n = b & 127, k = threadIdx.x;
    const float* W = layer ? W2 : W1;
    Wt[layer * 16384 + n * 128 + k] = __float2half_rn(W[k * 128 + n]);
}

// ---------------- batchnorm stats: atomic-free 2-stage reduction ----------------

__global__ __launch_bounds__(256) void bnstats_kernel(const __half* __restrict__ X,
                                                      float* __restrict__ partial) {
    __shared__ float red[4][256];
    int t = threadIdx.x;
    int f2 = t & 63, rg = t >> 6;
    const __half2* base = (const __half2*)X + f2;
    float s0 = 0.f, s1 = 0.f, q0 = 0.f, q1 = 0.f;
    for (int r = blockIdx.x * 4 + rg; r < NN; r += BNB * 4) {
        float2 v = __half22float2(base[(size_t)r * 64]);
        s0 += v.x; s1 += v.y; q0 += v.x * v.x; q1 += v.y * v.y;
    }
    red[rg][f2 * 4 + 0] = s0;
    red[rg][f2 * 4 + 1] = s1;
    red[rg][f2 * 4 + 2] = q0;
    red[rg][f2 * 4 + 3] = q1;
    __syncthreads();
    int kind = t >> 7, f = t & 127;
    int slot = (f >> 1) * 4 + (f & 1) + kind * 2;
    float v = red[0][slot] + red[1][slot] + red[2][slot] + red[3][slot];
    partial[blockIdx.x * 256 + kind * 128 + f] = v;
}

__global__ __launch_bounds__(256) void bnfinal_kernel(const float* __restrict__ partial,
                                                      const float* __restrict__ g,
                                                      const float* __restrict__ be,
                                                      float* __restrict__ sc) {
    __shared__ float red[256];
    int t = threadIdx.x;
    float v = 0.f;
    #pragma unroll 8
    for (int sl = 0; sl < BNB; ++sl) v += partial[sl * 256 + t];
    red[t] = v;
    __syncthreads();
    if (t < 128) {
        float s = red[t], q = red[128 + t];
        float mu  = s * (1.0f / NN);
        float var = q * (1.0f / NN) - mu * mu;
        float rstd = rsqrtf(var + EPSV);
        float scale = g[t] * rstd;
        sc[t]       = scale;
        sc[128 + t] = be[t] - mu * scale;
    }
}

// ---------------- MFMA fp16 GEMM: 64 nodes x 128 feats, K=128 ----------------

__device__ __forceinline__ int swzb(int row, int colByte) {
    return row * 256 + (colByte ^ ((row & 7) << 4));
}

template<bool BN, typename TIN>
__global__ __launch_bounds__(256) void gemm128m_kernel(const TIN* __restrict__ X,
        const __half* __restrict__ Wt, const float* __restrict__ sc,
        const float* __restrict__ dinv, __half* __restrict__ Y) {
    __shared__ __align__(16) char Xs[64 * 256];
    __shared__ __align__(16) char Wts[128 * 256];
    __shared__ float dvs[64];
    int tid = threadIdx.x;
    int node0 = blockIdx.x * 64;

    {   // stage Wt (pre-transposed fp16)
        int n = tid >> 1, c0 = (tid & 1) * 64;
        const _Float16* g = (const _Float16*)Wt + n * 128 + c0;
        #pragma unroll
        for (int j = 0; j < 8; ++j) {
            f16x8 v = *(const f16x8*)(g + j * 8);
            *(f16x8*)(Wts + swzb(n, (c0 + j * 8) * 2)) = v;
        }
    }
    {   // stage X (+BN+ReLU), cvt fp16
        int r = tid >> 2, c0 = (tid & 3) * 32;
        int grow = node0 + r;
        #pragma unroll
        for (int j = 0; j < 4; ++j) {
            int c = c0 + j * 8;
            f16x8 o;
            if (grow < NN) {
                float f[8];
                if constexpr (sizeof(TIN) == 4) {
                    float4 u0 = *(const float4*)((const float*)X + (size_t)grow * 128 + c);
                    float4 u1 = *(const float4*)((const float*)X + (size_t)grow * 128 + c + 4);
                    f[0] = u0.x; f[1] = u0.y; f[2] = u0.z; f[3] = u0.w;
                    f[4] = u1.x; f[5] = u1.y; f[6] = u1.z; f[7] = u1.w;
                } else {
                    f16x8 h = *(const f16x8*)((const _Float16*)X + (size_t)grow * 128 + c);
                    #pragma unroll
                    for (int i = 0; i < 8; ++i) f[i] = (float)h[i];
                }
                #pragma unroll
                for (int i = 0; i < 8; ++i) {
                    if constexpr (BN) f[i] = fmaxf(fmaf(f[i], sc[c + i], sc[128 + c + i]), 0.f);
                    o[i] = (_Float16)f[i];
                }
            } else {
                #pragma unroll
                for (int i = 0; i < 8; ++i) o[i] = (_Float16)0.f;
            }
            *(f16x8*)(Xs + swzb(r, c * 2)) = o;
        }
    }
    if (tid < 64) dvs[tid] = (node0 + tid < NN) ? dinv[node0 + tid] : 0.f;
    __syncthreads();

    int lane = tid & 63;
    int wv   = tid >> 6;
    int n0w  = wv * 32;
    int lm   = lane & 15;
    int lg   = lane >> 4;

    f32x4 acc[4][2] = {};
    #pragma unroll
    for (int s = 0; s < 4; ++s) {
        int kb = (s * 32 + lg * 8) * 2;
        f16x8 a[4], b[2];
        #pragma unroll
        for (int i = 0; i < 4; ++i)
            a[i] = *(const f16x8*)(Xs + swzb(i * 16 + lm, kb));
        #pragma unroll
        for (int r = 0; r < 2; ++r)
            b[r] = *(const f16x8*)(Wts + swzb(n0w + r * 16 + lm, kb));
        #pragma unroll
        for (int i = 0; i < 4; ++i)
            #pragma unroll
            for (int r = 0; r < 2; ++r)
                acc[i][r] = __builtin_amdgcn_mfma_f32_16x16x32_f16(a[i], b[r], acc[i][r], 0, 0, 0);
    }

    _Float16* Yh = (_Float16*)Y;
    #pragma unroll
    for (int i = 0; i < 4; ++i) {
        #pragma unroll
        for (int q = 0; q < 4; ++q) {
            int row = i * 16 + lg * 4 + q;
            int grow = node0 + row;
            if (grow < NN) {
                float di = dvs[row];
                Yh[(size_t)grow * 128 + n0w + lm]      = (_Float16)(acc[i][0][q] * di);
                Yh[(size_t)grow * 128 + n0w + 16 + lm] = (_Float16)(acc[i][1][q] * di);
            }
        }
    }
}

// ---------------- final dense GEMM 128->40 (fp32 VALU, fp16 in, tight 40 out) ----

__global__ __launch_bounds__(256) void gemm40_kernel(const __half* __restrict__ X,
        const float* __restrict__ W, const float* __restrict__ sc,
        const float* __restrict__ dinv, __half* __restrict__ Y) {
    __shared__ float Ws[128][40];
    __shared__ float Xs[32][132];
    int tx = threadIdx.x, ty = threadIdx.y;
    int tid = ty * 8 + tx;
    int node0 = blockIdx.x * 32;

    float* wf = &Ws[0][0];
    for (int idx = tid; idx < 128 * 40; idx += 256) wf[idx] = W[idx];
    for (int idx = tid * 8; idx < 32 * 128; idx += 256 * 8) {
        int n = idx >> 7, f = idx & 127;
        f16x8 h = *(const f16x8*)((const _Float16*)X + (size_t)(node0 + n) * 128 + f);
        float v[8];
        #pragma unroll
        for (int i = 0; i < 8; ++i)
            v[i] = fmaxf(fmaf((float)h[i], sc[f + i], sc[128 + f + i]), 0.f);
        *(float4*)&Xs[n][f]     = make_float4(v[0], v[1], v[2], v[3]);
        *(float4*)&Xs[n][f + 4] = make_float4(v[4], v[5], v[6], v[7]);
    }
    __syncthreads();

    float acc[5] = {0, 0, 0, 0, 0};
    int f0 = tx * 5;
    #pragma unroll 4
    for (int k = 0; k < 128; ++k) {
        float xv = Xs[ty][k];
        #pragma unroll
        for (int j = 0; j < 5; ++j) acc[j] = fmaf(xv, Ws[k][f0 + j], acc[j]);
    }
    float di = dinv[node0 + ty];
    __half* yp = Y + (size_t)(node0 + ty) * 40;   // tight stride 40
    #pragma unroll
    for (int j = 0; j < 5; ++j) yp[f0 + j] = __float2half_rn(acc[j] * di);
}

// ---------------- agg128: 16B/lane gather, fma_mix accumulate ----------------
// lane = 16*g + c : g = edge slot (0..3), c = 16-byte chunk (feats c*8..c*8+7)

__global__ __launch_bounds__(256) void agg128_kernel(const __half* __restrict__ H,
        const int* __restrict__ rowptr, const int* __restrict__ srcs,
        const float* __restrict__ dinv, const float* __restrict__ bias,
        __half* __restrict__ Bout) {
    int wave = threadIdx.x >> 6;
    int lane = threadIdx.x & 63;
    int node = blockIdx.x * 4 + wave;
    int beg = rowptr[node], end = rowptr[node + 1];
    int g = lane >> 4;          // edge slot
    int c = lane & 15;          // f16x8 chunk
    const f16x8* Hc = (const f16x8*)H + c;   // row r at Hc[r*16]
    float acc[8] = {};
    int e = beg;
    for (; e + 7 < end; e += 8) {            // 8 rows in flight (4 slots x 2)
        int s0 = srcs[e + g];
        int s1 = srcs[e + 4 + g];
        f16x8 h0 = Hc[(size_t)s0 * 16];
        f16x8 h1 = Hc[(size_t)s1 * 16];
        #pragma unroll
        for (int j = 0; j < 8; ++j) {
            acc[j] = fmaf((float)h0[j], 1.0f, acc[j]);   // v_fma_mix
            acc[j] = fmaf((float)h1[j], 1.0f, acc[j]);
        }
    }
    for (; e + 3 < end; e += 4) {
        int s0 = srcs[e + g];
        f16x8 h0 = Hc[(size_t)s0 * 16];
        #pragma unroll
        for (int j = 0; j < 8; ++j) acc[j] = fmaf((float)h0[j], 1.0f, acc[j]);
    }
    if (e + g < end) {
        int s = srcs[e + g];
        f16x8 h = Hc[(size_t)s * 16];
        #pragma unroll
        for (int j = 0; j < 8; ++j) acc[j] = fmaf((float)h[j], 1.0f, acc[j]);
    }
    // merge edge slots: xor 16, 32
    #pragma unroll
    for (int j = 0; j < 8; ++j) {
        acc[j] += __shfl_xor(acc[j], 16);
        acc[j] += __shfl_xor(acc[j], 32);
    }
    float di = dinv[node];
    f16x8 hs = Hc[(size_t)node * 16];        // self row (pre-scaled by dinv[node])
    _Float16 o[8];
    #pragma unroll
    for (int j = 0; j < 8; ++j) {
        float v = di * (acc[j] + (float)hs[j]) + bias[c * 8 + j];
        o[j] = (_Float16)v;
    }
    if (g == 0)
        *((f16x8*)Bout + (size_t)node * 16 + c) = *(f16x8*)o;
}

// ---------------- agg40: lane-per-feature scalar gather, tight 40-stride --------

__global__ __launch_bounds__(256) void agg40_softmax_kernel(const __half* __restrict__ H,
        const int* __restrict__ rowptr, const int* __restrict__ srcs,
        const float* __restrict__ dinv, const float* __restrict__ bias,
        float* __restrict__ out) {
    int wave = threadIdx.x >> 6;
    int lane = threadIdx.x & 63;
    int node = blockIdx.x * 4 + wave;
    int beg = rowptr[node], end = rowptr[node + 1];
    bool act = lane < 40;
    int ln = act ? lane : 0;
    const _Float16* Hc = (const _Float16*)H + ln;   // tight stride 40
    float a0 = 0.f, a1 = 0.f, a2 = 0.f, a3 = 0.f;
    float a4 = 0.f, a5 = 0.f, a6 = 0.f, a7 = 0.f;
    int e = beg;
    for (; e + 7 < end; e += 8) {
        a0 = fmaf((float)Hc[(size_t)srcs[e]     * 40], 1.0f, a0);
        a1 = fmaf((float)Hc[(size_t)srcs[e + 1] * 40], 1.0f, a1);
        a2 = fmaf((float)Hc[(size_t)srcs[e + 2] * 40], 1.0f, a2);
        a3 = fmaf((float)Hc[(size_t)srcs[e + 3] * 40], 1.0f, a3);
        a4 = fmaf((float)Hc[(size_t)srcs[e + 4] * 40], 1.0f, a4);
        a5 = fmaf((float)Hc[(size_t)srcs[e + 5] * 40], 1.0f, a5);
        a6 = fmaf((float)Hc[(size_t)srcs[e + 6] * 40], 1.0f, a6);
        a7 = fmaf((float)Hc[(size_t)srcs[e + 7] * 40], 1.0f, a7);
    }
    if (e + 3 < end) {
        a0 = fmaf((float)Hc[(size_t)srcs[e]     * 40], 1.0f, a0);
        a1 = fmaf((float)Hc[(size_t)srcs[e + 1] * 40], 1.0f, a1);
        a2 = fmaf((float)Hc[(size_t)srcs[e + 2] * 40], 1.0f, a2);
        a3 = fmaf((float)Hc[(size_t)srcs[e + 3] * 40], 1.0f, a3);
        e += 4;
    }
    for (; e < end; ++e) a0 = fmaf((float)Hc[(size_t)srcs[e] * 40], 1.0f, a0);
    float di = dinv[node];
    float hs = (float)Hc[(size_t)node * 40];
    float v = act ? (di * (a0 + a1 + a2 + a3 + a4 + a5 + a6 + a7 + hs) + bias[lane]) : -3.0e38f;
    float m = v;
    #pragma unroll
    for (int off = 32; off > 0; off >>= 1) m = fmaxf(m, __shfl_xor(m, off));
    float ev = act ? expf(v - m) : 0.f;
    float ssum = ev;
    #pragma unroll
    for (int off = 32; off > 0; off >>= 1) ssum += __shfl_xor(ssum, off);
    if (act) out[(size_t)node * 40 + lane] = ev / ssum;
}

// ---------------- launch ----------------

extern "C" void kernel_launch(void* const* d_in, const int* in_sizes, int n_in,
                              void* d_out, int out_size, void* d_ws, size_t ws_size,
                              hipStream_t stream) {
    const float* x   = (const float*)d_in[0];
    const int*   ei  = (const int*)d_in[1];
    const float* W1  = (const float*)d_in[2];
    const float* b1  = (const float*)d_in[3];
    const float* g1  = (const float*)d_in[4];
    const float* be1 = (const float*)d_in[5];
    const float* W2  = (const float*)d_in[6];
    const float* b2  = (const float*)d_in[7];
    const float* g2  = (const float*)d_in[8];
    const float* be2 = (const float*)d_in[9];
    const float* W3  = (const float*)d_in[10];
    const float* b3  = (const float*)d_in[11];
    float* out = (float*)d_out;
    const int* src = ei;
    const int* dst = ei + NE;

    char* p = (char*)d_ws;
    auto alloc = [&](size_t bytes) { char* r = p; p += (bytes + 255) & ~255ull; return r; };
    int*    rowptr    = (int*)   alloc((size_t)(NN + 1) * 4);
    int*    srcsorted = (int*)   alloc((size_t)NE * 4);
    float*  dinv      = (float*) alloc((size_t)NN * 4);
    float*  sc        = (float*) alloc(256 * 4);
    int*    G         = (int*)   alloc((size_t)GN * 4);
    int*    bsum      = (int*)   alloc((size_t)SNB * 4);
    float*  partial   = (float*) alloc((size_t)BNB * 256 * 4);
    __half* Wth       = (__half*)alloc((size_t)2 * 16384 * 2);
    __half* A         = (__half*)alloc((size_t)NN * 128 * 2);
    __half* Bh        = (__half*)alloc((size_t)NN * 128 * 2);
    int*    ebuf      = (int*)A;   // A unused until layer-1 GEMM

    // prep
    wprep_kernel<<<256, 128, 0, stream>>>(W1, W2, Wth);
    p1hist_kernel<<<NW1, 256, 0, stream>>>(dst, G);
    gscan1_kernel<<<SNB, 256, 0, stream>>>(G, bsum);
    gscan3_kernel<<<SNB, 256, 0, stream>>>(G, bsum);
    p1fill_kernel<<<NW1, 256, 0, stream>>>(src, dst, G, ebuf);
    p2build_kernel<<<NBUCK, 256, 0, stream>>>(ebuf, G, rowptr, srcsorted, dinv);

    const int GB = (NN + 63) / 64;   // 1563
    // layer 1
    gemm128m_kernel<false, float><<<GB, 256, 0, stream>>>(x, Wth, nullptr, dinv, A);
    agg128_kernel<<<NN / 4, 256, 0, stream>>>(A, rowptr, srcsorted, dinv, b1, Bh);
    bnstats_kernel<<<BNB, 256, 0, stream>>>(Bh, partial);
    bnfinal_kernel<<<1, 256, 0, stream>>>(partial, g1, be1, sc);
    // layer 2
    gemm128m_kernel<true, __half><<<GB, 256, 0, stream>>>(Bh, Wth + 16384, sc, dinv, A);
    agg128_kernel<<<NN / 4, 256, 0, stream>>>(A, rowptr, srcsorted, dinv, b2, Bh);
    bnstats_kernel<<<BNB, 256, 0, stream>>>(Bh, partial);
    bnfinal_kernel<<<1, 256, 0, stream>>>(partial, g2, be2, sc);
    // layer 3 (gemm40 writes tight 40-stride rows into A)
    gemm40_kernel<<<NN / 32, dim3(8, 32), 0, stream>>>(Bh, W3, sc, dinv, A);
    agg40_softmax_kernel<<<NN / 4, 256, 0, stream>>>(A, rowptr, srcsorted, dinv, b3, out);
}

// Round 15
// 398.175 us; speedup vs baseline: 1.0486x; 1.0078x over previous
//
#include <hip/hip_runtime.h>
#include <hip/hip_fp16.h>

#define NN   100000
#define NE   1600000
#define NBUCK 391                 // ceil(NN/256) buckets of 256 nodes
#define NW1   512                 // pass-1 workgroups
#define CH1   (NE / NW1)          // 3125 edges per wg
#define GN    (NBUCK * NW1)       // 200192 scan entries
#define SC    512
#define SNB   (GN / SC)           // 391 scan blocks
#define BNB   512                 // bnstats blocks
constexpr float EPSV = 1e-5f;

typedef _Float16 f16x8 __attribute__((ext_vector_type(8)));
typedef float    f32x4 __attribute__((ext_vector_type(4)));

// ---------------- graph prep: 2-level bucket CSR build ----------------

__global__ __launch_bounds__(256) void p1hist_kernel(const int* __restrict__ dst,
                                                     int* __restrict__ G) {
    __shared__ int h[NBUCK];
    int t = threadIdx.x, wg = blockIdx.x;
    for (int i = t; i < NBUCK; i += 256) h[i] = 0;
    __syncthreads();
    int base = wg * CH1;
    for (int e = base + t; e < base + CH1; e += 256)
        atomicAdd(&h[dst[e] >> 8], 1);
    __syncthreads();
    for (int i = t; i < NBUCK; i += 256) G[i * NW1 + wg] = h[i];
}

__global__ __launch_bounds__(256) void gscan1_kernel(const int* __restrict__ G,
                                                     int* __restrict__ bsum) {
    __shared__ int red[256];
    int t = threadIdx.x;
    int base = blockIdx.x * SC + t * 2;
    red[t] = G[base] + G[base + 1];
    __syncthreads();
    #pragma unroll
    for (int off = 128; off > 0; off >>= 1) {
        if (t < off) red[t] += red[t + off];
        __syncthreads();
    }
    if (t == 0) bsum[blockIdx.x] = red[0];
}

// scan of G in place; each block self-computes its prefix from bsum
__global__ __launch_bounds__(256) void gscan3_kernel(int* __restrict__ G,
                                                     const int* __restrict__ bsum) {
    __shared__ int pre[256];
    __shared__ int s[256];
    int t = threadIdx.x;
    int part = 0;
    for (int j = t; j < (int)blockIdx.x; j += 256) part += bsum[j];
    pre[t] = part;
    __syncthreads();
    #pragma unroll
    for (int off = 128; off > 0; off >>= 1) {
        if (t < off) pre[t] += pre[t + off];
        __syncthreads();
    }
    int boffv = pre[0];
    int base = blockIdx.x * SC + t * 2;
    int c0 = G[base], c1 = G[base + 1];
    int pair = c0 + c1;
    s[t] = pair;
    __syncthreads();
    #pragma unroll
    for (int off = 1; off < 256; off <<= 1) {
        int u = (t >= off) ? s[t - off] : 0;
        __syncthreads();
        s[t] += u;
        __syncthreads();
    }
    int excl = boffv + s[t] - pair;
    G[base]     = excl;
    G[base + 1] = excl + c0;
}

__global__ __launch_bounds__(256) void p1fill_kernel(const int* __restrict__ src,
                                                     const int* __restrict__ dst,
                                                     const int* __restrict__ G,
                                                     int* __restrict__ ebuf) {
    __shared__ int cur[NBUCK];
    int t = threadIdx.x, wg = blockIdx.x;
    for (int i = t; i < NBUCK; i += 256) cur[i] = G[i * NW1 + wg];
    __syncthreads();
    int base = wg * CH1;
    for (int e = base + t; e < base + CH1; e += 256) {
        int d = dst[e];
        int pos = atomicAdd(&cur[d >> 8], 1);
        ebuf[pos] = src[e] | ((d & 255) << 17);
    }
}

__global__ __launch_bounds__(256) void p2build_kernel(const int* __restrict__ ebuf,
                                                      const int* __restrict__ G,
                                                      int* __restrict__ rowptr,
                                                      int* __restrict__ srcsorted,
                                                      float* __restrict__ dinv) {
    __shared__ int cnt[256];
    __shared__ int s[256];
    __shared__ int cur[256];
    int t = threadIdx.x, b = blockIdx.x;
    int base = G[b * NW1];
    int endp = (b == NBUCK - 1) ? NE : G[(b + 1) * NW1];
    cnt[t] = 0;
    __syncthreads();
    for (int e = base + t; e < endp; e += 256)
        atomicAdd(&cnt[ebuf[e] >> 17], 1);
    __syncthreads();
    int c = cnt[t];
    s[t] = c;
    __syncthreads();
    #pragma unroll
    for (int off = 1; off < 256; off <<= 1) {
        int u = (t >= off) ? s[t - off] : 0;
        __syncthreads();
        s[t] += u;
        __syncthreads();
    }
    int excl = s[t] - c;
    int node = b * 256 + t;
    if (node < NN) {
        rowptr[node] = base + excl;
        dinv[node]   = rsqrtf((float)c + 1.0f);
    }
    cur[t] = base + excl;
    __syncthreads();
    for (int e = base + t; e < endp; e += 256) {
        int p = ebuf[e];
        int pos = atomicAdd(&cur[p >> 17], 1);
        srcsorted[pos] = p & 0x1FFFF;
    }
    if (b == NBUCK - 1 && t == 0) rowptr[NN] = NE;
}

// ---------------- weight prep: W[k][n] fp32 -> Wt[n][k] fp16 ----------------

__global__ void wprep_kernel(const float* __restrict__ W1, const float* __restrict__ W2,
                             __half* __restrict__ Wt) {
    int b = blockIdx.x;
    int layer = b >> 7, n = b & 127, k = threadIdx.x;
    const float* W = layer ? W2 : W1;
    Wt[layer * 16384 + n * 128 + k] = __float2half_rn(W[k * 128 + n]);
}

// ---------------- batchnorm stats: atomic-free 2-stage reduction ----------------

__global__ __launch_bounds__(256) void bnstats_kernel(const __half* __restrict__ X,
                                                      float* __restrict__ partial) {
    __shared__ float red[4][256];
    int t = threadIdx.x;
    int f2 = t & 63, rg = t >> 6;
    const __half2* base = (const __half2*)X + f2;
    float s0 = 0.f, s1 = 0.f, q0 = 0.f, q1 = 0.f;
    for (int r = blockIdx.x * 4 + rg; r < NN; r += BNB * 4) {
        float2 v = __half22float2(base[(size_t)r * 64]);
        s0 += v.x; s1 += v.y; q0 += v.x * v.x; q1 += v.y * v.y;
    }
    red[rg][f2 * 4 + 0] = s0;
    red[rg][f2 * 4 + 1] = s1;
    red[rg][f2 * 4 + 2] = q0;
    red[rg][f2 * 4 + 3] = q1;
    __syncthreads();
    int kind = t >> 7, f = t & 127;
    int slot = (f >> 1) * 4 + (f & 1) + kind * 2;
    float v = red[0][slot] + red[1][slot] + red[2][slot] + red[3][slot];
    partial[blockIdx.x * 256 + kind * 128 + f] = v;
}

__global__ __launch_bounds__(256) void bnfinal_kernel(const float* __restrict__ partial,
                                                      const float* __restrict__ g,
                                                      const float* __restrict__ be,
                                                      float* __restrict__ sc) {
    __shared__ float red[256];
    int t = threadIdx.x;
    float v = 0.f;
    #pragma unroll 8
    for (int sl = 0; sl < BNB; ++sl) v += partial[sl * 256 + t];
    red[t] = v;
    __syncthreads();
    if (t < 128) {
        float s = red[t], q = red[128 + t];
        float mu  = s * (1.0f / NN);
        float var = q * (1.0f / NN) - mu * mu;
        float rstd = rsqrtf(var + EPSV);
        float scale = g[t] * rstd;
        sc[t]       = scale;
        sc[128 + t] = be[t] - mu * scale;
    }
}

// ---------------- MFMA fp16 GEMM: 64 nodes x 128 feats, K=128 ----------------
// B-fragments read directly from L2-resident Wt (no LDS stage) -> 16.4KB LDS,
// 8 blocks/CU occupancy.

__device__ __forceinline__ int swzb(int row, int colByte) {
    return row * 256 + (colByte ^ ((row & 7) << 4));
}

template<bool BN, typename TIN>
__global__ __launch_bounds__(256) void gemm128m_kernel(const TIN* __restrict__ X,
        const __half* __restrict__ Wt, const float* __restrict__ sc,
        const float* __restrict__ dinv, __half* __restrict__ Y) {
    __shared__ __align__(16) char Xs[64 * 256];
    __shared__ float dvs[64];
    int tid = threadIdx.x;
    int node0 = blockIdx.x * 64;

    {   // stage X (+BN+ReLU), cvt fp16
        int r = tid >> 2, c0 = (tid & 3) * 32;
        int grow = node0 + r;
        #pragma unroll
        for (int j = 0; j < 4; ++j) {
            int c = c0 + j * 8;
            f16x8 o;
            if (grow < NN) {
                float f[8];
                if constexpr (sizeof(TIN) == 4) {
                    float4 u0 = *(const float4*)((const float*)X + (size_t)grow * 128 + c);
                    float4 u1 = *(const float4*)((const float*)X + (size_t)grow * 128 + c + 4);
                    f[0] = u0.x; f[1] = u0.y; f[2] = u0.z; f[3] = u0.w;
                    f[4] = u1.x; f[5] = u1.y; f[6] = u1.z; f[7] = u1.w;
                } else {
                    f16x8 h = *(const f16x8*)((const _Float16*)X + (size_t)grow * 128 + c);
                    #pragma unroll
                    for (int i = 0; i < 8; ++i) f[i] = (float)h[i];
                }
                #pragma unroll
                for (int i = 0; i < 8; ++i) {
                    if constexpr (BN) f[i] = fmaxf(fmaf(f[i], sc[c + i], sc[128 + c + i]), 0.f);
                    o[i] = (_Float16)f[i];
                }
            } else {
                #pragma unroll
                for (int i = 0; i < 8; ++i) o[i] = (_Float16)0.f;
            }
            *(f16x8*)(Xs + swzb(r, c * 2)) = o;
        }
    }
    if (tid < 64) dvs[tid] = (node0 + tid < NN) ? dinv[node0 + tid] : 0.f;
    __syncthreads();

    int lane = tid & 63;
    int wv   = tid >> 6;
    int n0w  = wv * 32;
    int lm   = lane & 15;
    int lg   = lane >> 4;
    const _Float16* Wg = (const _Float16*)Wt;

    f32x4 acc[4][2] = {};
    #pragma unroll
    for (int s = 0; s < 4; ++s) {
        int kk = s * 32 + lg * 8;
        f16x8 a[4], b[2];
        #pragma unroll
        for (int r = 0; r < 2; ++r)
            b[r] = *(const f16x8*)(Wg + (size_t)(n0w + r * 16 + lm) * 128 + kk);
        #pragma unroll
        for (int i = 0; i < 4; ++i)
            a[i] = *(const f16x8*)(Xs + swzb(i * 16 + lm, kk * 2));
        #pragma unroll
        for (int i = 0; i < 4; ++i)
            #pragma unroll
            for (int r = 0; r < 2; ++r)
                acc[i][r] = __builtin_amdgcn_mfma_f32_16x16x32_f16(a[i], b[r], acc[i][r], 0, 0, 0);
    }

    _Float16* Yh = (_Float16*)Y;
    #pragma unroll
    for (int i = 0; i < 4; ++i) {
        #pragma unroll
        for (int q = 0; q < 4; ++q) {
            int row = i * 16 + lg * 4 + q;
            int grow = node0 + row;
            if (grow < NN) {
                float di = dvs[row];
                Yh[(size_t)grow * 128 + n0w + lm]      = (_Float16)(acc[i][0][q] * di);
                Yh[(size_t)grow * 128 + n0w + 16 + lm] = (_Float16)(acc[i][1][q] * di);
            }
        }
    }
}

// ---------------- final dense GEMM 128->40 (fp32 VALU, fp16 in, tight 40 out) ----

__global__ __launch_bounds__(256) void gemm40_kernel(const __half* __restrict__ X,
        const float* __restrict__ W, const float* __restrict__ sc,
        const float* __restrict__ dinv, __half* __restrict__ Y) {
    __shared__ float Ws[128][40];
    __shared__ float Xs[32][132];
    int tx = threadIdx.x, ty = threadIdx.y;
    int tid = ty * 8 + tx;
    int node0 = blockIdx.x * 32;

    float* wf = &Ws[0][0];
    for (int idx = tid; idx < 128 * 40; idx += 256) wf[idx] = W[idx];
    for (int idx = tid * 8; idx < 32 * 128; idx += 256 * 8) {
        int n = idx >> 7, f = idx & 127;
        f16x8 h = *(const f16x8*)((const _Float16*)X + (size_t)(node0 + n) * 128 + f);
        float v[8];
        #pragma unroll
        for (int i = 0; i < 8; ++i)
            v[i] = fmaxf(fmaf((float)h[i], sc[f + i], sc[128 + f + i]), 0.f);
        *(float4*)&Xs[n][f]     = make_float4(v[0], v[1], v[2], v[3]);
        *(float4*)&Xs[n][f + 4] = make_float4(v[4], v[5], v[6], v[7]);
    }
    __syncthreads();

    float acc[5] = {0, 0, 0, 0, 0};
    int f0 = tx * 5;
    #pragma unroll 4
    for (int k = 0; k < 128; ++k) {
        float xv = Xs[ty][k];
        #pragma unroll
        for (int j = 0; j < 5; ++j) acc[j] = fmaf(xv, Ws[k][f0 + j], acc[j]);
    }
    float di = dinv[node0 + ty];
    __half* yp = Y + (size_t)(node0 + ty) * 40;   // tight stride 40
    #pragma unroll
    for (int j = 0; j < 5; ++j) yp[f0 + j] = __float2half_rn(acc[j] * di);
}

// ---------------- agg128: 16B/lane gather, 16 rows in flight ----------------
// lane = 16*g + c : g = edge slot (0..3), c = 16-byte chunk (feats c*8..c*8+7)

__global__ __launch_bounds__(256) void agg128_kernel(const __half* __restrict__ H,
        const int* __restrict__ rowptr, const int* __restrict__ srcs,
        const float* __restrict__ dinv, const float* __restrict__ bias,
        __half* __restrict__ Bout) {
    int wave = threadIdx.x >> 6;
    int lane = threadIdx.x & 63;
    int node = blockIdx.x * 4 + wave;
    int beg = rowptr[node], end = rowptr[node + 1];
    int g = lane >> 4;          // edge slot
    int c = lane & 15;          // f16x8 chunk
    const f16x8* Hc = (const f16x8*)H + c;   // row r at Hc[r*16]
    float acc[8] = {};
    int e = beg;
    for (; e + 15 < end; e += 16) {          // 16 rows in flight (4 slots x 4)
        int s0 = srcs[e + g];
        int s1 = srcs[e + 4 + g];
        int s2 = srcs[e + 8 + g];
        int s3 = srcs[e + 12 + g];
        f16x8 h0 = Hc[(size_t)s0 * 16];
        f16x8 h1 = Hc[(size_t)s1 * 16];
        f16x8 h2 = Hc[(size_t)s2 * 16];
        f16x8 h3 = Hc[(size_t)s3 * 16];
        #pragma unroll
        for (int j = 0; j < 8; ++j)
            acc[j] += ((float)h0[j] + (float)h1[j]) + ((float)h2[j] + (float)h3[j]);
    }
    for (; e + 7 < end; e += 8) {
        int s0 = srcs[e + g];
        int s1 = srcs[e + 4 + g];
        f16x8 h0 = Hc[(size_t)s0 * 16];
        f16x8 h1 = Hc[(size_t)s1 * 16];
        #pragma unroll
        for (int j = 0; j < 8; ++j) acc[j] += (float)h0[j] + (float)h1[j];
    }
    for (; e + 3 < end; e += 4) {
        int s0 = srcs[e + g];
        f16x8 h0 = Hc[(size_t)s0 * 16];
        #pragma unroll
        for (int j = 0; j < 8; ++j) acc[j] += (float)h0[j];
    }
    if (e + g < end) {
        int s = srcs[e + g];
        f16x8 h = Hc[(size_t)s * 16];
        #pragma unroll
        for (int j = 0; j < 8; ++j) acc[j] += (float)h[j];
    }
    // merge edge slots: xor 16, 32
    #pragma unroll
    for (int j = 0; j < 8; ++j) {
        acc[j] += __shfl_xor(acc[j], 16);
        acc[j] += __shfl_xor(acc[j], 32);
    }
    float di = dinv[node];
    f16x8 hs = Hc[(size_t)node * 16];        // self row (pre-scaled by dinv[node])
    _Float16 o[8];
    #pragma unroll
    for (int j = 0; j < 8; ++j) {
        float v = di * (acc[j] + (float)hs[j]) + bias[c * 8 + j];
        o[j] = (_Float16)v;
    }
    if (g == 0)
        *((f16x8*)Bout + (size_t)node * 16 + c) = *(f16x8*)o;
}

// ---------------- agg40: lane-per-feature scalar gather, tight 40-stride --------

__global__ __launch_bounds__(256) void agg40_softmax_kernel(const __half* __restrict__ H,
        const int* __restrict__ rowptr, const int* __restrict__ srcs,
        const float* __restrict__ dinv, const float* __restrict__ bias,
        float* __restrict__ out) {
    int wave = threadIdx.x >> 6;
    int lane = threadIdx.x & 63;
    int node = blockIdx.x * 4 + wave;
    int beg = rowptr[node], end = rowptr[node + 1];
    bool act = lane < 40;
    int ln = act ? lane : 0;
    const _Float16* Hc = (const _Float16*)H + ln;   // tight stride 40
    float a0 = 0.f, a1 = 0.f, a2 = 0.f, a3 = 0.f;
    float a4 = 0.f, a5 = 0.f, a6 = 0.f, a7 = 0.f;
    int e = beg;
    for (; e + 7 < end; e += 8) {
        a0 += (float)Hc[(size_t)srcs[e]     * 40];
        a1 += (float)Hc[(size_t)srcs[e + 1] * 40];
        a2 += (float)Hc[(size_t)srcs[e + 2] * 40];
        a3 += (float)Hc[(size_t)srcs[e + 3] * 40];
        a4 += (float)Hc[(size_t)srcs[e + 4] * 40];
        a5 += (float)Hc[(size_t)srcs[e + 5] * 40];
        a6 += (float)Hc[(size_t)srcs[e + 6] * 40];
        a7 += (float)Hc[(size_t)srcs[e + 7] * 40];
    }
    if (e + 3 < end) {
        a0 += (float)Hc[(size_t)srcs[e]     * 40];
        a1 += (float)Hc[(size_t)srcs[e + 1] * 40];
        a2 += (float)Hc[(size_t)srcs[e + 2] * 40];
        a3 += (float)Hc[(size_t)srcs[e + 3] * 40];
        e += 4;
    }
    for (; e < end; ++e) a0 += (float)Hc[(size_t)srcs[e] * 40];
    float di = dinv[node];
    float hs = (float)Hc[(size_t)node * 40];
    float v = act ? (di * (a0 + a1 + a2 + a3 + a4 + a5 + a6 + a7 + hs) + bias[lane]) : -3.0e38f;
    float m = v;
    #pragma unroll
    for (int off = 32; off > 0; off >>= 1) m = fmaxf(m, __shfl_xor(m, off));
    float ev = act ? expf(v - m) : 0.f;
    float ssum = ev;
    #pragma unroll
    for (int off = 32; off > 0; off >>= 1) ssum += __shfl_xor(ssum, off);
    if (act) out[(size_t)node * 40 + lane] = ev / ssum;
}

// ---------------- launch ----------------

extern "C" void kernel_launch(void* const* d_in, const int* in_sizes, int n_in,
                              void* d_out, int out_size, void* d_ws, size_t ws_size,
                              hipStream_t stream) {
    const float* x   = (const float*)d_in[0];
    const int*   ei  = (const int*)d_in[1];
    const float* W1  = (const float*)d_in[2];
    const float* b1  = (const float*)d_in[3];
    const float* g1  = (const float*)d_in[4];
    const float* be1 = (const float*)d_in[5];
    const float* W2  = (const float*)d_in[6];
    const float* b2  = (const float*)d_in[7];
    const float* g2  = (const float*)d_in[8];
    const float* be2 = (const float*)d_in[9];
    const float* W3  = (const float*)d_in[10];
    const float* b3  = (const float*)d_in[11];
    float* out = (float*)d_out;
    const int* src = ei;
    const int* dst = ei + NE;

    char* p = (char*)d_ws;
    auto alloc = [&](size_t bytes) { char* r = p; p += (bytes + 255) & ~255ull; return r; };
    int*    rowptr    = (int*)   alloc((size_t)(NN + 1) * 4);
    int*    srcsorted = (int*)   alloc((size_t)NE * 4);
    float*  dinv      = (float*) alloc((size_t)NN * 4);
    float*  sc        = (float*) alloc(256 * 4);
    int*    G         = (int*)   alloc((size_t)GN * 4);
    int*    bsum      = (int*)   alloc((size_t)SNB * 4);
    float*  partial   = (float*) alloc((size_t)BNB * 256 * 4);
    __half* Wth       = (__half*)alloc((size_t)2 * 16384 * 2);
    __half* A         = (__half*)alloc((size_t)NN * 128 * 2);
    __half* Bh        = (__half*)alloc((size_t)NN * 128 * 2);
    int*    ebuf      = (int*)A;   // A unused until layer-1 GEMM

    // prep
    wprep_kernel<<<256, 128, 0, stream>>>(W1, W2, Wth);
    p1hist_kernel<<<NW1, 256, 0, stream>>>(dst, G);
    gscan1_kernel<<<SNB, 256, 0, stream>>>(G, bsum);
    gscan3_kernel<<<SNB, 256, 0, stream>>>(G, bsum);
    p1fill_kernel<<<NW1, 256, 0, stream>>>(src, dst, G, ebuf);
    p2build_kernel<<<NBUCK, 256, 0, stream>>>(ebuf, G, rowptr, srcsorted, dinv);

    const int GB = (NN + 63) / 64;   // 1563
    // layer 1
    gemm128m_kernel<false, float><<<GB, 256, 0, stream>>>(x, Wth, nullptr, dinv, A);
    agg128_kernel<<<NN / 4, 256, 0, stream>>>(A, rowptr, srcsorted, dinv, b1, Bh);
    bnstats_kernel<<<BNB, 256, 0, stream>>>(Bh, partial);
    bnfinal_kernel<<<1, 256, 0, stream>>>(partial, g1, be1, sc);
    // layer 2
    gemm128m_kernel<true, __half><<<GB, 256, 0, stream>>>(Bh, Wth + 16384, sc, dinv, A);
    agg128_kernel<<<NN / 4, 256, 0, stream>>>(A, rowptr, srcsorted, dinv, b2, Bh);
    bnstats_kernel<<<BNB, 256, 0, stream>>>(Bh, partial);
    bnfinal_kernel<<<1, 256, 0, stream>>>(partial, g2, be2, sc);
    // layer 3 (gemm40 writes tight 40-stride rows into A)
    gemm40_kernel<<<NN / 32, dim3(8, 32), 0, stream>>>(Bh, W3, sc, dinv, A);
    agg40_softmax_kernel<<<NN / 4, 256, 0, stream>>>(A, rowptr, srcsorted, dinv, b3, out);
}